// Round 8
// baseline (390.373 us; speedup 1.0000x reference)
//
#include <hip/hip_runtime.h>
#include <stdint.h>

#define HD 768
#define NHEADS 12
#define DHEAD 64
#define BATCH 8
#define TLEN 64
#define ILEN 197
#define NPAIRS 100864   // = 394*256 exactly
#define MTILES 394

typedef __attribute__((ext_vector_type(8))) short short8;
typedef __attribute__((ext_vector_type(4))) float f32x4;

__device__ __forceinline__ short f2bf(float x) {
    union { float f; uint32_t u; } v; v.f = x;
    uint32_t r = v.u + 0x7FFFu + ((v.u >> 16) & 1u);
    return (short)(r >> 16);
}
__device__ __forceinline__ float bf2f(short s) {
    union { uint32_t u; float f; } v; v.u = ((uint32_t)(unsigned short)s) << 16;
    return v.f;
}
__device__ __forceinline__ void gll16(const void* g, void* l) {
    __builtin_amdgcn_global_load_lds(
        (const __attribute__((address_space(1))) unsigned int*)g,
        (__attribute__((address_space(3))) unsigned int*)l, 16, 0, 0);
}

// ---------------------------------------------------------------------------
// Prep: W5s proj chunks (unchanged) + W1Bs gate-GEMM B chunks (BK=32).
// W1Bs: 72 chunks (pn 0..2, kt32 0..23) of [256 col][32 k] bf16, 16 KB each,
//   byte within chunk = col*64 + ((kg*16) ^ ((col&3)<<4)) + e*2, kg=k/8.
// Linear gll16 of a chunk reproduces the swizzled LDS image.
// ---------------------------------------------------------------------------
__global__ __launch_bounds__(256) void prep_weights(
    const float* __restrict__ Wq, const float* __restrict__ Wk,
    const float* __restrict__ Wv, const float* __restrict__ Wt,
    const float* __restrict__ Wi, const float* __restrict__ W1,
    short* __restrict__ W5s, short* __restrict__ W1Bs)
{
    __shared__ float tile[64][65];
    int bx = blockIdx.x;
    int tid = threadIdx.x;
    if (bx >= 720) {
        int idx = bx - 720;            // 0..71
        int pn = idx / 24, kt = idx - pn * 24;   // kt = BK32 tile
        int c = tid;                   // col 0..255
        int j = pn * 256 + c;
        char* dst = (char*)W1Bs + (size_t)idx * 16384 + c * 64;
        int swz = (c & 3) << 4;
#pragma unroll
        for (int kg = 0; kg < 4; ++kg) {
            short8 o;
#pragma unroll
            for (int e = 0; e < 8; ++e)
                o[e] = f2bf(W1[(size_t)(kt * 32 + kg * 8 + e) * HD + j]);
            *(short8*)(dst + ((kg * 16) ^ swz)) = o;
        }
        return;
    }
    int seg = bx / 144, ti = bx - seg * 144;
    const float* src = (seg == 0) ? Wt : (seg == 1) ? Wq : (seg == 2) ? Wi
                     : (seg == 3) ? Wk : Wv;
    int kt = ti / 12, ntile = ti - kt * 12;
#pragma unroll
    for (int pass = 0; pass < 16; ++pass) {
        int idx = pass * 256 + tid;
        int kk = idx >> 6, nn = idx & 63;
        tile[kk][nn] = src[(size_t)(kt * 64 + kk) * HD + ntile * 64 + nn];
    }
    __syncthreads();
    size_t base = ((size_t)(seg * 12 + ntile) * 12 + kt) * 8192;
#pragma unroll
    for (int pass = 0; pass < 16; ++pass) {
        int idx = pass * 256 + tid;
        int col = idx >> 6, kloc = idx & 63;
        float x = tile[kloc][col];
        short h = f2bf(x);
        short lw = f2bf(x - bf2f(h));
        int sidx = (col * 64 + kloc) ^ ((col & 7) << 3);
        W5s[base + sidx] = h;
        W5s[base + 4096 + sidx] = lw;
    }
}

// ---------------------------------------------------------------------------
// Projection GEMM (hi/lo bf16 split, near-fp32) — unchanged from R3.
// ---------------------------------------------------------------------------
__global__ __launch_bounds__(256, 1) void proj_kernel(
    const float* __restrict__ X, int M,
    const short* __restrict__ W5s, int segbase,
    const float* __restrict__ bias0, const float* __restrict__ bias1,
    const float* __restrict__ bias2,
    float* __restrict__ out0, float* __restrict__ out1, float* __restrict__ out2)
{
    __shared__ __align__(16) short Bs[2][8192];
    int tid = threadIdx.x;
    int l = tid & 63, w = tid >> 6;
    int lo = l & 15, grp = l >> 4;
    int y = blockIdx.y;
    int segl = y / 12, ntile = y - segl * 12;
    int seg = segbase + segl;
    const char* wsrc = (const char*)W5s + (size_t)((seg * 12 + ntile) * 12) * 16384;
    {
        const char* s = wsrc + w * 4096 + l * 16;
        char* d = (char*)&Bs[0][0] + w * 4096;
        gll16(s, d); gll16(s + 1024, d + 1024);
        gll16(s + 2048, d + 2048); gll16(s + 3072, d + 3072);
    }
    int arow = blockIdx.x * 64 + w * 16 + lo;
    bool aok = arow < M;
    const float* xrow = X + (size_t)(aok ? arow : 0) * HD;
    short8 ah[24], al[24];
#pragma unroll
    for (int kc = 0; kc < 24; ++kc) {
        int kb = kc * 32 + grp * 8;
        float4 xa = {0.f, 0.f, 0.f, 0.f}, xb = {0.f, 0.f, 0.f, 0.f};
        if (aok) { xa = *(const float4*)(xrow + kb); xb = *(const float4*)(xrow + kb + 4); }
        float xs[8] = {xa.x, xa.y, xa.z, xa.w, xb.x, xb.y, xb.z, xb.w};
#pragma unroll
        for (int e = 0; e < 8; ++e) {
            short hh = f2bf(xs[e]);
            ah[kc][e] = hh;
            al[kc][e] = f2bf(xs[e] - bf2f(hh));
        }
    }
    __syncthreads();

    f32x4 acc[4];
    f32x4 z4 = {0.f, 0.f, 0.f, 0.f};
#pragma unroll
    for (int js = 0; js < 4; ++js) acc[js] = z4;

#pragma unroll
    for (int kk = 0; kk < 12; ++kk) {
        const short* buf = &Bs[kk & 1][0];
        if (kk < 11) {
            const char* s = wsrc + (size_t)(kk + 1) * 16384 + w * 4096 + l * 16;
            char* d = (char*)&Bs[(kk + 1) & 1][0] + w * 4096;
            gll16(s, d); gll16(s + 1024, d + 1024);
            gll16(s + 2048, d + 2048); gll16(s + 3072, d + 3072);
            asm volatile("s_waitcnt vmcnt(4)" ::: "memory");
        } else {
            asm volatile("s_waitcnt vmcnt(0)" ::: "memory");
        }
        __builtin_amdgcn_s_barrier();
        asm volatile("" ::: "memory");
#pragma unroll
        for (int js = 0; js < 4; ++js) {
            int col = js * 16 + lo;
            int base = col * 64;
            int sw = (col & 7) << 3;
#pragma unroll
            for (int kcl = 0; kcl < 2; ++kcl) {
                int idx = (base + kcl * 32 + grp * 8) ^ sw;
                short8 bh = *(const short8*)&buf[idx];
                short8 bl = *(const short8*)&buf[4096 + idx];
                int kc = kk * 2 + kcl;
                acc[js] = __builtin_amdgcn_mfma_f32_16x16x32_bf16(ah[kc], bh, acc[js], 0, 0, 0);
                acc[js] = __builtin_amdgcn_mfma_f32_16x16x32_bf16(ah[kc], bl, acc[js], 0, 0, 0);
                acc[js] = __builtin_amdgcn_mfma_f32_16x16x32_bf16(al[kc], bh, acc[js], 0, 0, 0);
            }
        }
        asm volatile("s_waitcnt lgkmcnt(0)" ::: "memory");
        __builtin_amdgcn_s_barrier();
        asm volatile("" ::: "memory");
    }
    const float* bp = (segl == 0) ? bias0 : (segl == 1) ? bias1 : bias2;
    float* op = (segl == 0) ? out0 : (segl == 1) ? out1 : out2;
#pragma unroll
    for (int js = 0; js < 4; ++js) {
        int cc = ntile * 64 + js * 16 + lo;
        float bvv = bp[cc];
#pragma unroll
        for (int r = 0; r < 4; ++r) {
            int orow = blockIdx.x * 64 + w * 16 + grp * 4 + r;
            if (orow < M) op[(size_t)orow * HD + cc] = acc[js][r] + bvv;
        }
    }
}

// ---------------------------------------------------------------------------
// build_a: materialize A = bf16(te ⊙ ie) into pre-swizzled 16 KB BK32 chunks:
// chunk (m_l, kt32); byte = row*64 + ((kg*16) ^ ((row&3)<<4)) + e*2.
// One block per (m_l, kt64); writes the two BK32 chunks. thread = row (pair).
// ---------------------------------------------------------------------------
__global__ __launch_bounds__(256) void build_a(
    const float* __restrict__ te, const float* __restrict__ ie,
    short* __restrict__ As, int mstart)
{
    int bx = blockIdx.x;
    int m_l = bx / 12, kt = bx - m_l * 12;     // kt = BK64 pair of chunks
    int tid = threadIdx.x;
    int p = (mstart + m_l) * 256 + tid;
    int b = p / 12608; int rr = p - b * 12608;
    int t = rr / 197;  int i = rr - t * 197;
    const float* tp = te + (size_t)(b * 64 + t) * HD + kt * 64;
    const float* ip = ie + (size_t)(b * 197 + i) * HD + kt * 64;
    int swz = (tid & 3) << 4;
#pragma unroll
    for (int h = 0; h < 2; ++h) {
        char* dst = (char*)As + ((size_t)(m_l * 24 + kt * 2 + h) * 16384) + tid * 64;
#pragma unroll
        for (int kg = 0; kg < 4; ++kg) {
            int kb = h * 32 + kg * 8;
            float4 xa = *(const float4*)(ip + kb);
            float4 xb = *(const float4*)(ip + kb + 4);
            float4 ta = *(const float4*)(tp + kb);
            float4 tb = *(const float4*)(tp + kb + 4);
            short8 o;
            o[0] = f2bf(xa.x * ta.x); o[1] = f2bf(xa.y * ta.y);
            o[2] = f2bf(xa.z * ta.z); o[3] = f2bf(xa.w * ta.w);
            o[4] = f2bf(xb.x * tb.x); o[5] = f2bf(xb.y * tb.y);
            o[6] = f2bf(xb.z * tb.z); o[7] = f2bf(xb.w * tb.w);
            *(short8*)(dst + ((kg * 16) ^ swz)) = o;
        }
    }
}

// ---------------------------------------------------------------------------
// gate_gemm: 256x256 tile, BK=32, 8 waves (2Mx4N), per-wave 128x64 out.
// R8: 4-deep LDS ring (4 slots x (16KB A + 16KB B) = 128 KB): stage tile k+3
// while computing tile k -> counted vmcnt(8) boundary (2 tiles in flight),
// never a vmcnt(0) drain until the tail. One barrier per K-step.
// Slot safety: stage(k+3) -> slot (k+3)&3 = slot of tile k-1, freed by the
// step-k barrier; its old gll16 writes retired by the k-1 boundary wait.
// ---------------------------------------------------------------------------
__global__ __launch_bounds__(512, 2) void gate_gemm(
    const short* __restrict__ As, const short* __restrict__ W1Bs,
    const float* __restrict__ b1, const float* __restrict__ W2,
    float* __restrict__ plg, int mstart)
{
    __shared__ __align__(16) char lds[131072];   // A slots [0,64K), B slots [64K,128K)
    int tid = threadIdx.x;
    int lane = tid & 63, wid = tid >> 6;
    int lo = lane & 15, grp = lane >> 4;
    int wr = wid >> 2, wc = wid & 3;
    // bijective XCD swizzle (m204): hw bx -> logical id
    int bx0 = blockIdx.x;
    int nwg = gridDim.x;
    int qq = nwg >> 3, rr8 = nwg & 7;
    int xcd = bx0 & 7;
    int logical = (xcd < rr8 ? xcd * (qq + 1) : rr8 * (qq + 1) + (xcd - rr8) * qq)
                + (bx0 >> 3);
    int m_l = logical / 3, pn = logical - m_l * 3;

    const char* Ag = (const char*)As + (size_t)m_l * 24 * 16384;
    const char* Bg = (const char*)W1Bs + (size_t)pn * 24 * 16384;

    // stage tile tt into ring slot tt&3 (4 gll16 per thread: A x2, B x2)
    auto stage = [&](int tt) {
        int s = (tt & 3) * 16384;
        const char* sa = Ag + (size_t)tt * 16384 + tid * 16;
        const char* sb = Bg + (size_t)tt * 16384 + tid * 16;
        gll16(sa,        lds + s + tid * 16);
        gll16(sa + 8192, lds + s + 8192 + tid * 16);
        gll16(sb,        lds + 65536 + s + tid * 16);
        gll16(sb + 8192, lds + 65536 + s + 8192 + tid * 16);
    };
    stage(0); stage(1); stage(2);   // 12 loads in flight

    f32x4 acc[8][4];
    f32x4 z4 = {0.f, 0.f, 0.f, 0.f};
#pragma unroll
    for (int rt = 0; rt < 8; ++rt)
#pragma unroll
        for (int ct = 0; ct < 4; ++ct) acc[rt][ct] = z4;
    int swz = (lo & 3) << 4;

    for (int k = 0; k < 24; ++k) {
        // boundary: tile k landed (counted — keep k+1,k+2 in flight)
        if (k <= 21)      asm volatile("s_waitcnt vmcnt(8)" ::: "memory");
        else if (k == 22) asm volatile("s_waitcnt vmcnt(4)" ::: "memory");
        else              asm volatile("s_waitcnt vmcnt(0)" ::: "memory");
        __builtin_amdgcn_s_barrier();
        asm volatile("" ::: "memory");
        if (k + 3 < 24) stage(k + 3);

        int sA = (k & 3) * 16384;
        int sB = 65536 + (k & 3) * 16384;
        short8 bfr[4];
#pragma unroll
        for (int ct = 0; ct < 4; ++ct) {
            int c = wc * 64 + ct * 16 + lo;
            bfr[ct] = *(const short8*)(lds + sB + c * 64 + ((grp * 16) ^ swz));
        }
#pragma unroll
        for (int q = 0; q < 4; ++q) {
            short8 af[2];
#pragma unroll
            for (int i2 = 0; i2 < 2; ++i2) {
                int r = wr * 128 + (2 * q + i2) * 16 + lo;
                af[i2] = *(const short8*)(lds + sA + r * 64 + ((grp * 16) ^ swz));
            }
            __builtin_amdgcn_s_setprio(1);
#pragma unroll
            for (int i2 = 0; i2 < 2; ++i2)
#pragma unroll
                for (int ct = 0; ct < 4; ++ct)
                    acc[2 * q + i2][ct] = __builtin_amdgcn_mfma_f32_16x16x32_bf16(
                        af[i2], bfr[ct], acc[2 * q + i2][ct], 0, 0, 0);
            __builtin_amdgcn_s_setprio(0);
        }
    }

    // epilogue: h = relu(acc + b1); per-wave partial logit over its 64 cols
    float b1v[4], w2v[4];
#pragma unroll
    for (int ct = 0; ct < 4; ++ct) {
        int j = pn * 256 + wc * 64 + ct * 16 + lo;
        b1v[ct] = b1[j]; w2v[ct] = W2[j];
    }
    float pl[8][4];
#pragma unroll
    for (int rt = 0; rt < 8; ++rt)
#pragma unroll
        for (int r = 0; r < 4; ++r) {
            float s = 0.f;
#pragma unroll
            for (int ct = 0; ct < 4; ++ct)
                s += fmaxf(acc[rt][ct][r] + b1v[ct], 0.f) * w2v[ct];
            pl[rt][r] = s;
        }
#pragma unroll
    for (int msk = 1; msk <= 8; msk <<= 1)
#pragma unroll
        for (int rt = 0; rt < 8; ++rt)
#pragma unroll
            for (int r = 0; r < 4; ++r)
                pl[rt][r] += __shfl_xor(pl[rt][r], msk);

    // reduce the 4 wc-wave partials through (now dead) LDS
    __syncthreads();
    float* red = (float*)lds;                       // [8 wid][128 row]
    if (lo == 0) {
#pragma unroll
        for (int rt = 0; rt < 8; ++rt)
#pragma unroll
            for (int r = 0; r < 4; ++r)
                red[wid * 128 + rt * 16 + grp * 4 + r] = pl[rt][r];
    }
    __syncthreads();
    if (tid < 256) {
        int wr_ = tid >> 7, rl = tid & 127;
        float s = red[(wr_ * 4 + 0) * 128 + rl] + red[(wr_ * 4 + 1) * 128 + rl]
                + red[(wr_ * 4 + 2) * 128 + rl] + red[(wr_ * 4 + 3) * 128 + rl];
        plg[(size_t)pn * NPAIRS + (size_t)(mstart + m_l) * 256 + tid] = s;
    }
}

// ---------------------------------------------------------------------------
__global__ __launch_bounds__(256) void gate_fin(
    const float* __restrict__ plg, const float* __restrict__ b2,
    float* __restrict__ gateb)
{
    int idx = blockIdx.x * 256 + threadIdx.x;
    if (idx < NPAIRS) {
        float s = plg[idx] + plg[NPAIRS + idx] + plg[2 * NPAIRS + idx] + b2[0];
        gateb[idx] = 1.f / (1.f + __expf(-s));
    }
}

// ---------------------------------------------------------------------------
// Cross-attention, fp32 VALU. Grid = (b,h,t-quarter) = 384 blocks. Unchanged.
// ---------------------------------------------------------------------------
__global__ __launch_bounds__(256) void attn_kernel(
    const float* __restrict__ q, const float* __restrict__ k,
    const float* __restrict__ v, const float* __restrict__ gate,
    float* __restrict__ out)
{
    __shared__ float k_s[ILEN * 65];
    __shared__ float p_s[4][200];
    int bx = blockIdx.x;
    int tq = bx & 3;
    int h = (bx >> 2) % NHEADS;
    int b = bx / (4 * NHEADS);
    int tid = threadIdx.x;
    for (int idx = tid; idx < ILEN * DHEAD; idx += 256) {
        int i = idx >> 6, d = idx & 63;
        k_s[i * 65 + d] = k[(size_t)(b * ILEN + i) * HD + h * DHEAD + d];
    }
    __syncthreads();

    int l = tid & 63, w = tid >> 6;
    for (int tt = 0; tt < 4; ++tt) {
        int t = tq * 16 + w * 4 + tt;
        float qv = q[(size_t)(b * 64 + t) * HD + h * DHEAD + l];
        float s0 = 0.f, s1 = 0.f, s2 = 0.f, s3 = 0.f;
        int i0 = l, i1 = 64 + l, i2 = 128 + l;
        int i3c = (192 + l < ILEN) ? 192 + l : 0;
        for (int d = 0; d < 64; ++d) {
            float qd = __shfl(qv, d);
            s0 += qd * k_s[i0 * 65 + d];
            s1 += qd * k_s[i1 * 65 + d];
            s2 += qd * k_s[i2 * 65 + d];
            s3 += qd * k_s[i3c * 65 + d];
        }
        float sc[4] = {s0, s1, s2, s3};
        float m = -3.0e38f;
#pragma unroll
        for (int rep = 0; rep < 4; ++rep) {
            int i = rep * 64 + l;
            sc[rep] = (i < ILEN) ? sc[rep] * 0.125f : -3.0e38f;
            m = fmaxf(m, sc[rep]);
        }
        for (int mask = 32; mask >= 1; mask >>= 1) m = fmaxf(m, __shfl_xor(m, mask));
        float sum = 0.f;
#pragma unroll
        for (int rep = 0; rep < 4; ++rep) {
            float e = __expf(sc[rep] - m);
            sc[rep] = e;
            sum += e;
        }
        for (int mask = 32; mask >= 1; mask >>= 1) sum += __shfl_xor(sum, mask);
        float inv = 1.f / sum;
        const float* grow = gate + (size_t)(b * 64 + t) * ILEN;
#pragma unroll
        for (int rep = 0; rep < 4; ++rep) {
            int i = rep * 64 + l;
            if (i < 200) p_s[w][i] = (i < ILEN) ? sc[rep] * inv * grow[i] : 0.f;
        }
        float ctx = 0.f;
        const float* vbase = v + (size_t)(b * ILEN) * HD + h * DHEAD + l;
        for (int c = 0; c < 49; ++c) {
            float4 p4 = *(const float4*)&p_s[w][c * 4];
            ctx += p4.x * vbase[(size_t)(c * 4 + 0) * HD];
            ctx += p4.y * vbase[(size_t)(c * 4 + 1) * HD];
            ctx += p4.z * vbase[(size_t)(c * 4 + 2) * HD];
            ctx += p4.w * vbase[(size_t)(c * 4 + 3) * HD];
        }
        {
            float4 p4 = *(const float4*)&p_s[w][196];
            ctx += p4.x * vbase[(size_t)196 * HD];
        }
        out[(size_t)(b * 64 + t) * HD + h * DHEAD + l] = ctx;
    }
}

// ---------------------------------------------------------------------------
extern "C" void kernel_launch(void* const* d_in, const int* in_sizes, int n_in,
                              void* d_out, int out_size, void* d_ws, size_t ws_size,
                              hipStream_t stream)
{
    const float* text  = (const float*)d_in[0];
    const float* image = (const float*)d_in[1];
    const float* Wq = (const float*)d_in[2];
    const float* bq = (const float*)d_in[3];
    const float* Wk = (const float*)d_in[4];
    const float* bk = (const float*)d_in[5];
    const float* Wv = (const float*)d_in[6];
    const float* bv = (const float*)d_in[7];
    const float* Wt = (const float*)d_in[8];
    const float* bt = (const float*)d_in[9];
    const float* Wi = (const float*)d_in[10];
    const float* bi = (const float*)d_in[11];
    const float* W1 = (const float*)d_in[12];
    const float* b1 = (const float*)d_in[13];
    const float* W2 = (const float*)d_in[14];
    const float* b2 = (const float*)d_in[15];
    float* out = (float*)d_out;

    char* ws = (char*)d_ws;
    size_t off = 0;
    auto carve = [&](size_t bytes) -> void* {
        void* p = (void*)(ws + off);
        off += (bytes + 255) & ~(size_t)255;
        return p;
    };
    short* W5s  = (short*)carve((size_t)5 * 144 * 8192 * 2);   // 11.8 MB
    short* W1Bs = (short*)carve((size_t)72 * 16384);           // 1.18 MB
    float* te    = (float*)carve((size_t)512 * 768 * 4);
    float* qb    = (float*)carve((size_t)512 * 768 * 4);
    float* ieb   = (float*)carve((size_t)1576 * 768 * 4);
    float* kb    = (float*)carve((size_t)1576 * 768 * 4);
    float* vb    = (float*)carve((size_t)1576 * 768 * 4);
    float* gateb = (float*)carve((size_t)NPAIRS * 4);
    float* plg   = (float*)carve((size_t)3 * NPAIRS * 4);

    // A buffer: as many M-tiles as workspace allows (stripe loop)
    size_t per_m = (size_t)24 * 16384;                          // 384 KB per M-tile
    size_t avail = (ws_size > off) ? (ws_size - off) : 0;
    int stripe = (int)(avail / per_m);
    if (stripe > MTILES) stripe = MTILES;
    if (stripe < 1) stripe = 1;
    short* As = (short*)(ws + off);
    int nst = (MTILES + stripe - 1) / stripe;

    hipLaunchKernelGGL(prep_weights, dim3(792), dim3(256), 0, stream,
                       Wq, Wk, Wv, Wt, Wi, W1, W5s, W1Bs);
    hipLaunchKernelGGL(proj_kernel, dim3(8, 24), dim3(256), 0, stream,
                       text, 512, W5s, 0, bt, bq, (const float*)nullptr,
                       te, qb, (float*)nullptr);
    hipLaunchKernelGGL(proj_kernel, dim3(25, 36), dim3(256), 0, stream,
                       image, 1576, W5s, 2, bi, bk, bv,
                       ieb, kb, vb);
    for (int s = 0; s < nst; ++s) {
        int m0 = s * stripe;
        int mc = (MTILES - m0 < stripe) ? (MTILES - m0) : stripe;
        hipLaunchKernelGGL(build_a, dim3(mc * 12), dim3(256), 0, stream,
                           te, ieb, As, m0);
        hipLaunchKernelGGL(gate_gemm, dim3(mc * 3), dim3(512), 0, stream,
                           As, W1Bs, b1, W2, plg, m0);
    }
    hipLaunchKernelGGL(gate_fin, dim3((NPAIRS + 255) / 256), dim3(256), 0, stream,
                       plg, b2, gateb);
    hipLaunchKernelGGL(attn_kernel, dim3(BATCH * NHEADS * 4), dim3(256), 0, stream,
                       qb, kb, vb, gateb, out);
}

// Round 9
// 346.619 us; speedup vs baseline: 1.1262x; 1.1262x over previous
//
#include <hip/hip_runtime.h>
#include <stdint.h>

#define HD 768
#define NHEADS 12
#define DHEAD 64
#define BATCH 8
#define TLEN 64
#define ILEN 197
#define NPAIRS 100864   // = 394*256 exactly
#define MTILES 394

typedef __attribute__((ext_vector_type(8))) short short8;
typedef __attribute__((ext_vector_type(4))) float f32x4;

__device__ __forceinline__ short f2bf(float x) {
    union { float f; uint32_t u; } v; v.f = x;
    uint32_t r = v.u + 0x7FFFu + ((v.u >> 16) & 1u);
    return (short)(r >> 16);
}
__device__ __forceinline__ float bf2f(short s) {
    union { uint32_t u; float f; } v; v.u = ((uint32_t)(unsigned short)s) << 16;
    return v.f;
}
__device__ __forceinline__ void gll16(const void* g, void* l) {
    __builtin_amdgcn_global_load_lds(
        (const __attribute__((address_space(1))) unsigned int*)g,
        (__attribute__((address_space(3))) unsigned int*)l, 16, 0, 0);
}

// ---------------------------------------------------------------------------
// Prep: W5s proj chunks (unchanged) + W1Bs gate-GEMM B chunks (BK=64, R7).
// W1Bs: 36 chunks (pn 0..2, kt 0..11) of [256 col][64 k] bf16, 32 KB each,
//   byte within chunk = c*128 + ((kg*16) ^ ((c&7)<<4)); linear gll16-compatible.
// (row&7)<<4 XOR spans all 32 banks across 8 rows -> conflict-free b128.
// ---------------------------------------------------------------------------
__global__ __launch_bounds__(256) void prep_weights(
    const float* __restrict__ Wq, const float* __restrict__ Wk,
    const float* __restrict__ Wv, const float* __restrict__ Wt,
    const float* __restrict__ Wi, const float* __restrict__ W1,
    short* __restrict__ W5s, short* __restrict__ W1Bs)
{
    __shared__ float tile[64][65];
    int bx = blockIdx.x;
    int tid = threadIdx.x;
    if (bx >= 720) {
        int idx = bx - 720;            // 0..35
        int pn = idx / 12, kt = idx - pn * 12;
        int c = tid;                   // col 0..255
        int j = pn * 256 + c;
        char* dst = (char*)W1Bs + (size_t)idx * 32768 + c * 128;
        int swz = (c & 7) << 4;
#pragma unroll
        for (int kg = 0; kg < 8; ++kg) {
            short8 o;
#pragma unroll
            for (int e = 0; e < 8; ++e)
                o[e] = f2bf(W1[(size_t)(kt * 64 + kg * 8 + e) * HD + j]);
            *(short8*)(dst + ((kg * 16) ^ swz)) = o;
        }
        return;
    }
    int seg = bx / 144, ti = bx - seg * 144;
    const float* src = (seg == 0) ? Wt : (seg == 1) ? Wq : (seg == 2) ? Wi
                     : (seg == 3) ? Wk : Wv;
    int kt = ti / 12, ntile = ti - kt * 12;
#pragma unroll
    for (int pass = 0; pass < 16; ++pass) {
        int idx = pass * 256 + tid;
        int kk = idx >> 6, nn = idx & 63;
        tile[kk][nn] = src[(size_t)(kt * 64 + kk) * HD + ntile * 64 + nn];
    }
    __syncthreads();
    size_t base = ((size_t)(seg * 12 + ntile) * 12 + kt) * 8192;
#pragma unroll
    for (int pass = 0; pass < 16; ++pass) {
        int idx = pass * 256 + tid;
        int col = idx >> 6, kloc = idx & 63;
        float x = tile[kloc][col];
        short h = f2bf(x);
        short lw = f2bf(x - bf2f(h));
        int sidx = (col * 64 + kloc) ^ ((col & 7) << 3);
        W5s[base + sidx] = h;
        W5s[base + 4096 + sidx] = lw;
    }
}

// ---------------------------------------------------------------------------
// Projection GEMM (hi/lo bf16 split, near-fp32) — unchanged from R3.
// ---------------------------------------------------------------------------
__global__ __launch_bounds__(256, 1) void proj_kernel(
    const float* __restrict__ X, int M,
    const short* __restrict__ W5s, int segbase,
    const float* __restrict__ bias0, const float* __restrict__ bias1,
    const float* __restrict__ bias2,
    float* __restrict__ out0, float* __restrict__ out1, float* __restrict__ out2)
{
    __shared__ __align__(16) short Bs[2][8192];
    int tid = threadIdx.x;
    int l = tid & 63, w = tid >> 6;
    int lo = l & 15, grp = l >> 4;
    int y = blockIdx.y;
    int segl = y / 12, ntile = y - segl * 12;
    int seg = segbase + segl;
    const char* wsrc = (const char*)W5s + (size_t)((seg * 12 + ntile) * 12) * 16384;
    {
        const char* s = wsrc + w * 4096 + l * 16;
        char* d = (char*)&Bs[0][0] + w * 4096;
        gll16(s, d); gll16(s + 1024, d + 1024);
        gll16(s + 2048, d + 2048); gll16(s + 3072, d + 3072);
    }
    int arow = blockIdx.x * 64 + w * 16 + lo;
    bool aok = arow < M;
    const float* xrow = X + (size_t)(aok ? arow : 0) * HD;
    short8 ah[24], al[24];
#pragma unroll
    for (int kc = 0; kc < 24; ++kc) {
        int kb = kc * 32 + grp * 8;
        float4 xa = {0.f, 0.f, 0.f, 0.f}, xb = {0.f, 0.f, 0.f, 0.f};
        if (aok) { xa = *(const float4*)(xrow + kb); xb = *(const float4*)(xrow + kb + 4); }
        float xs[8] = {xa.x, xa.y, xa.z, xa.w, xb.x, xb.y, xb.z, xb.w};
#pragma unroll
        for (int e = 0; e < 8; ++e) {
            short hh = f2bf(xs[e]);
            ah[kc][e] = hh;
            al[kc][e] = f2bf(xs[e] - bf2f(hh));
        }
    }
    __syncthreads();

    f32x4 acc[4];
    f32x4 z4 = {0.f, 0.f, 0.f, 0.f};
#pragma unroll
    for (int js = 0; js < 4; ++js) acc[js] = z4;

#pragma unroll
    for (int kk = 0; kk < 12; ++kk) {
        const short* buf = &Bs[kk & 1][0];
        if (kk < 11) {
            const char* s = wsrc + (size_t)(kk + 1) * 16384 + w * 4096 + l * 16;
            char* d = (char*)&Bs[(kk + 1) & 1][0] + w * 4096;
            gll16(s, d); gll16(s + 1024, d + 1024);
            gll16(s + 2048, d + 2048); gll16(s + 3072, d + 3072);
            asm volatile("s_waitcnt vmcnt(4)" ::: "memory");
        } else {
            asm volatile("s_waitcnt vmcnt(0)" ::: "memory");
        }
        __builtin_amdgcn_s_barrier();
        asm volatile("" ::: "memory");
#pragma unroll
        for (int js = 0; js < 4; ++js) {
            int col = js * 16 + lo;
            int base = col * 64;
            int sw = (col & 7) << 3;
#pragma unroll
            for (int kcl = 0; kcl < 2; ++kcl) {
                int idx = (base + kcl * 32 + grp * 8) ^ sw;
                short8 bh = *(const short8*)&buf[idx];
                short8 bl = *(const short8*)&buf[4096 + idx];
                int kc = kk * 2 + kcl;
                acc[js] = __builtin_amdgcn_mfma_f32_16x16x32_bf16(ah[kc], bh, acc[js], 0, 0, 0);
                acc[js] = __builtin_amdgcn_mfma_f32_16x16x32_bf16(ah[kc], bl, acc[js], 0, 0, 0);
                acc[js] = __builtin_amdgcn_mfma_f32_16x16x32_bf16(al[kc], bh, acc[js], 0, 0, 0);
            }
        }
        asm volatile("s_waitcnt lgkmcnt(0)" ::: "memory");
        __builtin_amdgcn_s_barrier();
        asm volatile("" ::: "memory");
    }
    const float* bp = (segl == 0) ? bias0 : (segl == 1) ? bias1 : bias2;
    float* op = (segl == 0) ? out0 : (segl == 1) ? out1 : out2;
#pragma unroll
    for (int js = 0; js < 4; ++js) {
        int cc = ntile * 64 + js * 16 + lo;
        float bvv = bp[cc];
#pragma unroll
        for (int r = 0; r < 4; ++r) {
            int orow = blockIdx.x * 64 + w * 16 + grp * 4 + r;
            if (orow < M) op[(size_t)orow * HD + cc] = acc[js][r] + bvv;
        }
    }
}

// ---------------------------------------------------------------------------
// build_a: materialize A = bf16(te ⊙ ie) into pre-swizzled 32 KB K-tile
// chunks (R7 layout): byte = r*128 + ((kg*16) ^ ((r&7)<<4)).
// ---------------------------------------------------------------------------
__global__ __launch_bounds__(256) void build_a(
    const float* __restrict__ te, const float* __restrict__ ie,
    short* __restrict__ As, int mstart)
{
    int bx = blockIdx.x;
    int m_l = bx / 12, kt = bx - m_l * 12;
    int tid = threadIdx.x;
    int p = (mstart + m_l) * 256 + tid;
    int b = p / 12608; int rr = p - b * 12608;
    int t = rr / 197;  int i = rr - t * 197;
    const float* tp = te + (size_t)(b * 64 + t) * HD + kt * 64;
    const float* ip = ie + (size_t)(b * 197 + i) * HD + kt * 64;
    char* dst = (char*)As + ((size_t)(m_l * 12 + kt) * 32768) + tid * 128;
    int swz = (tid & 7) << 4;
#pragma unroll
    for (int kg = 0; kg < 8; ++kg) {
        float4 xa = *(const float4*)(ip + kg * 8);
        float4 xb = *(const float4*)(ip + kg * 8 + 4);
        float4 ta = *(const float4*)(tp + kg * 8);
        float4 tb = *(const float4*)(tp + kg * 8 + 4);
        short8 o;
        o[0] = f2bf(xa.x * ta.x); o[1] = f2bf(xa.y * ta.y);
        o[2] = f2bf(xa.z * ta.z); o[3] = f2bf(xa.w * ta.w);
        o[4] = f2bf(xb.x * tb.x); o[5] = f2bf(xb.y * tb.y);
        o[6] = f2bf(xb.z * tb.z); o[7] = f2bf(xb.w * tb.w);
        *(short8*)(dst + ((kg * 16) ^ swz)) = o;
    }
}

// ---------------------------------------------------------------------------
// gate_gemm: 256x256 tile, BK=64, 8 waves (2Mx4N), per-wave 128x64 out.
// R9: R7 conflict-free layout + m201-style phase pacing: per K-tile 4
// quadrant-phases, each {ds_read af (+bfr at q0) || stage 2 gll16 of kt+1 ->
// barrier -> lgkmcnt(0)+sched_barrier -> setprio(1) 16 MFMA setprio(0) ->
// barrier}. Staging drain = covered vmcnt(0) folded into phase 3 (loads get
// 1-4 phases of cover). XCD swizzle kept.
// ---------------------------------------------------------------------------
__global__ __launch_bounds__(512, 2) void gate_gemm(
    const short* __restrict__ As, const short* __restrict__ W1Bs,
    const float* __restrict__ b1, const float* __restrict__ W2,
    float* __restrict__ plg, int mstart)
{
    __shared__ __align__(16) char lds[131072];   // A dbuf [0,64K), B dbuf [64K,128K)
    int tid = threadIdx.x;
    int lane = tid & 63, wid = tid >> 6;
    int lo = lane & 15, grp = lane >> 4;
    int wr = wid >> 2, wc = wid & 3;
    // bijective XCD swizzle (m204): hw bx -> logical id
    int bx0 = blockIdx.x;
    int nwg = gridDim.x;
    int qq = nwg >> 3, rr8 = nwg & 7;
    int xcd = bx0 & 7;
    int logical = (xcd < rr8 ? xcd * (qq + 1) : rr8 * (qq + 1) + (xcd - rr8) * qq)
                + (bx0 >> 3);
    int m_l = logical / 3, pn = logical - m_l * 3;

    const char* Ag = (const char*)As + (size_t)m_l * 12 * 32768;
    const char* Bg = (const char*)W1Bs + (size_t)pn * 12 * 32768;

    // prologue: stage K-tile 0 into parity 0, drain, sync
    {
        gll16(Ag + tid * 16,          lds + tid * 16);
        gll16(Ag + 8192 + tid * 16,   lds + 8192 + tid * 16);
        gll16(Ag + 16384 + tid * 16,  lds + 16384 + tid * 16);
        gll16(Ag + 24576 + tid * 16,  lds + 24576 + tid * 16);
        gll16(Bg + tid * 16,          lds + 65536 + tid * 16);
        gll16(Bg + 8192 + tid * 16,   lds + 65536 + 8192 + tid * 16);
        gll16(Bg + 16384 + tid * 16,  lds + 65536 + 16384 + tid * 16);
        gll16(Bg + 24576 + tid * 16,  lds + 65536 + 24576 + tid * 16);
    }
    asm volatile("s_waitcnt vmcnt(0)" ::: "memory");
    __builtin_amdgcn_s_barrier();
    asm volatile("" ::: "memory");

    f32x4 acc[8][4];
    f32x4 z4 = {0.f, 0.f, 0.f, 0.f};
#pragma unroll
    for (int rt = 0; rt < 8; ++rt)
#pragma unroll
        for (int ct = 0; ct < 4; ++ct) acc[rt][ct] = z4;
    int swz = (lo & 7) << 4;

    for (int kt = 0; kt < 12; ++kt) {
        int par = kt & 1, npar = par ^ 1;
        int aoff = par * 32768;
        int boff = 65536 + par * 32768;
        bool more = kt < 11;
        const char* Aun = Ag + (size_t)(kt + 1) * 32768;
        const char* Bun = Bg + (size_t)(kt + 1) * 32768;
        int dA = npar * 32768, dB = 65536 + npar * 32768;

        short8 bfr[4][2];
#pragma unroll
        for (int q = 0; q < 4; ++q) {
            // --- phase q: ds reads + 2 staging gll16, then barrier/MFMA ---
            short8 af[2][2];
#pragma unroll
            for (int i2 = 0; i2 < 2; ++i2) {
                int r = wr * 128 + (2 * q + i2) * 16 + lo;
#pragma unroll
                for (int ks = 0; ks < 2; ++ks)
                    af[i2][ks] = *(const short8*)(lds + aoff + r * 128 + ((ks * 64 + grp * 16) ^ swz));
            }
            if (q == 0) {
#pragma unroll
                for (int ct = 0; ct < 4; ++ct) {
                    int c = wc * 64 + ct * 16 + lo;
#pragma unroll
                    for (int ks = 0; ks < 2; ++ks)
                        bfr[ct][ks] = *(const short8*)(lds + boff + c * 128 + ((ks * 64 + grp * 16) ^ swz));
                }
            }
            if (more) {
                if (q < 2) {
                    gll16(Aun + (size_t)(q * 2) * 8192 + tid * 16,
                          lds + dA + (q * 2) * 8192 + tid * 16);
                    gll16(Aun + (size_t)(q * 2 + 1) * 8192 + tid * 16,
                          lds + dA + (q * 2 + 1) * 8192 + tid * 16);
                } else {
                    gll16(Bun + (size_t)((q - 2) * 2) * 8192 + tid * 16,
                          lds + dB + ((q - 2) * 2) * 8192 + tid * 16);
                    gll16(Bun + (size_t)((q - 2) * 2 + 1) * 8192 + tid * 16,
                          lds + dB + ((q - 2) * 2 + 1) * 8192 + tid * 16);
                }
            }
            asm volatile("" ::: "memory");
            __builtin_amdgcn_s_barrier();
            asm volatile("s_waitcnt lgkmcnt(0)" ::: "memory");
            __builtin_amdgcn_sched_barrier(0);
            __builtin_amdgcn_s_setprio(1);
#pragma unroll
            for (int i2 = 0; i2 < 2; ++i2)
#pragma unroll
                for (int ct = 0; ct < 4; ++ct)
#pragma unroll
                    for (int ks = 0; ks < 2; ++ks)
                        acc[2 * q + i2][ct] = __builtin_amdgcn_mfma_f32_16x16x32_bf16(
                            af[i2][ks], bfr[ct][ks], acc[2 * q + i2][ct], 0, 0, 0);
            __builtin_amdgcn_s_setprio(0);
            if (q == 3) {   // covered drain: kt+1's 8 loads had 1-4 phases to land
                asm volatile("s_waitcnt vmcnt(0)" ::: "memory");
            }
            __builtin_amdgcn_s_barrier();
            asm volatile("" ::: "memory");
        }
    }

    // epilogue: h = relu(acc + b1); per-wave partial logit over its 64 cols
    float b1v[4], w2v[4];
#pragma unroll
    for (int ct = 0; ct < 4; ++ct) {
        int j = pn * 256 + wc * 64 + ct * 16 + lo;
        b1v[ct] = b1[j]; w2v[ct] = W2[j];
    }
    float pl[8][4];
#pragma unroll
    for (int rt = 0; rt < 8; ++rt)
#pragma unroll
        for (int r = 0; r < 4; ++r) {
            float s = 0.f;
#pragma unroll
            for (int ct = 0; ct < 4; ++ct)
                s += fmaxf(acc[rt][ct][r] + b1v[ct], 0.f) * w2v[ct];
            pl[rt][r] = s;
        }
#pragma unroll
    for (int msk = 1; msk <= 8; msk <<= 1)
#pragma unroll
        for (int rt = 0; rt < 8; ++rt)
#pragma unroll
            for (int r = 0; r < 4; ++r)
                pl[rt][r] += __shfl_xor(pl[rt][r], msk);

    // reduce the 4 wc-wave partials through (now dead) LDS
    __syncthreads();
    float* red = (float*)lds;                       // [8 wid][128 row]
    if (lo == 0) {
#pragma unroll
        for (int rt = 0; rt < 8; ++rt)
#pragma unroll
            for (int r = 0; r < 4; ++r)
                red[wid * 128 + rt * 16 + grp * 4 + r] = pl[rt][r];
    }
    __syncthreads();
    if (tid < 256) {
        int wr_ = tid >> 7, rl = tid & 127;
        float s = red[(wr_ * 4 + 0) * 128 + rl] + red[(wr_ * 4 + 1) * 128 + rl]
                + red[(wr_ * 4 + 2) * 128 + rl] + red[(wr_ * 4 + 3) * 128 + rl];
        plg[(size_t)pn * NPAIRS + (size_t)(mstart + m_l) * 256 + tid] = s;
    }
}

// ---------------------------------------------------------------------------
__global__ __launch_bounds__(256) void gate_fin(
    const float* __restrict__ plg, const float* __restrict__ b2,
    float* __restrict__ gateb)
{
    int idx = blockIdx.x * 256 + threadIdx.x;
    if (idx < NPAIRS) {
        float s = plg[idx] + plg[NPAIRS + idx] + plg[2 * NPAIRS + idx] + b2[0];
        gateb[idx] = 1.f / (1.f + __expf(-s));
    }
}

// ---------------------------------------------------------------------------
// Cross-attention, fp32 VALU. Grid = (b,h,t-quarter) = 384 blocks.
// R9: all 4 softmax rows per wave computed first into p_s[w][i][4], then one
// PV pass over i reads each v-row ONCE for 4 t's (was 4x v traffic).
// ---------------------------------------------------------------------------
__global__ __launch_bounds__(256) void attn_kernel(
    const float* __restrict__ q, const float* __restrict__ k,
    const float* __restrict__ v, const float* __restrict__ gate,
    float* __restrict__ out)
{
    __shared__ float k_s[ILEN * 65];
    __shared__ float p_s[4][ILEN][4];   // [wave][i][tt]
    int bx = blockIdx.x;
    int tq = bx & 3;
    int h = (bx >> 2) % NHEADS;
    int b = bx / (4 * NHEADS);
    int tid = threadIdx.x;
    for (int idx = tid; idx < ILEN * DHEAD; idx += 256) {
        int i = idx >> 6, d = idx & 63;
        k_s[i * 65 + d] = k[(size_t)(b * ILEN + i) * HD + h * DHEAD + d];
    }
    __syncthreads();

    int l = tid & 63, w = tid >> 6;
    int tbase = tq * 16 + w * 4;

    // ---- scores + softmax + gate for this wave's 4 t rows ----
    for (int tt = 0; tt < 4; ++tt) {
        int t = tbase + tt;
        float qv = q[(size_t)(b * 64 + t) * HD + h * DHEAD + l];
        float s0 = 0.f, s1 = 0.f, s2 = 0.f, s3 = 0.f;
        int i0 = l, i1 = 64 + l, i2 = 128 + l;
        int i3c = (192 + l < ILEN) ? 192 + l : 0;
        for (int d = 0; d < 64; ++d) {
            float qd = __shfl(qv, d);
            s0 += qd * k_s[i0 * 65 + d];
            s1 += qd * k_s[i1 * 65 + d];
            s2 += qd * k_s[i2 * 65 + d];
            s3 += qd * k_s[i3c * 65 + d];
        }
        float sc[4] = {s0, s1, s2, s3};
        float m = -3.0e38f;
#pragma unroll
        for (int rep = 0; rep < 4; ++rep) {
            int i = rep * 64 + l;
            sc[rep] = (i < ILEN) ? sc[rep] * 0.125f : -3.0e38f;
            m = fmaxf(m, sc[rep]);
        }
        for (int mask = 32; mask >= 1; mask >>= 1) m = fmaxf(m, __shfl_xor(m, mask));
        float sum = 0.f;
#pragma unroll
        for (int rep = 0; rep < 4; ++rep) {
            float e = __expf(sc[rep] - m);
            sc[rep] = e;
            sum += e;
        }
        for (int mask = 32; mask >= 1; mask >>= 1) sum += __shfl_xor(sum, mask);
        float inv = 1.f / sum;
        const float* grow = gate + (size_t)(b * 64 + t) * ILEN;
#pragma unroll
        for (int rep = 0; rep < 4; ++rep) {
            int i = rep * 64 + l;
            if (i < ILEN) p_s[w][i][tt] = sc[rep] * inv * grow[i];
        }
    }
    // same wave writes & reads p_s -> no barrier needed

    // ---- PV: one pass over i; each v row feeds 4 t's ----
    float ctx[4] = {0.f, 0.f, 0.f, 0.f};
    const float* vbase = v + (size_t)(b * ILEN) * HD + h * DHEAD + l;
#pragma unroll 4
    for (int i = 0; i < ILEN; ++i) {
        float vv = vbase[(size_t)i * HD];
        float4 p4 = *(const float4*)&p_s[w][i][0];
        ctx[0] += p4.x * vv;
        ctx[1] += p4.y * vv;
        ctx[2] += p4.z * vv;
        ctx[3] += p4.w * vv;
    }
#pragma unroll
    for (int tt = 0; tt < 4; ++tt)
        out[(size_t)(b * 64 + tbase + tt) * HD + h * DHEAD + l] = ctx[tt];
}

// ---------------------------------------------------------------------------
extern "C" void kernel_launch(void* const* d_in, const int* in_sizes, int n_in,
                              void* d_out, int out_size, void* d_ws, size_t ws_size,
                              hipStream_t stream)
{
    const float* text  = (const float*)d_in[0];
    const float* image = (const float*)d_in[1];
    const float* Wq = (const float*)d_in[2];
    const float* bq = (const float*)d_in[3];
    const float* Wk = (const float*)d_in[4];
    const float* bk = (const float*)d_in[5];
    const float* Wv = (const float*)d_in[6];
    const float* bv = (const float*)d_in[7];
    const float* Wt = (const float*)d_in[8];
    const float* bt = (const float*)d_in[9];
    const float* Wi = (const float*)d_in[10];
    const float* bi = (const float*)d_in[11];
    const float* W1 = (const float*)d_in[12];
    const float* b1 = (const float*)d_in[13];
    const float* W2 = (const float*)d_in[14];
    const float* b2 = (const float*)d_in[15];
    float* out = (float*)d_out;

    char* ws = (char*)d_ws;
    size_t off = 0;
    auto carve = [&](size_t bytes) -> void* {
        void* p = (void*)(ws + off);
        off += (bytes + 255) & ~(size_t)255;
        return p;
    };
    short* W5s  = (short*)carve((size_t)5 * 144 * 8192 * 2);   // 11.8 MB
    short* W1Bs = (short*)carve((size_t)36 * 32768);           // 1.18 MB
    float* te    = (float*)carve((size_t)512 * 768 * 4);
    float* qb    = (float*)carve((size_t)512 * 768 * 4);
    float* ieb   = (float*)carve((size_t)1576 * 768 * 4);
    float* kb    = (float*)carve((size_t)1576 * 768 * 4);
    float* vb    = (float*)carve((size_t)1576 * 768 * 4);
    float* gateb = (float*)carve((size_t)NPAIRS * 4);
    float* plg   = (float*)carve((size_t)3 * NPAIRS * 4);

    // A buffer: as many M-tiles as workspace allows (stripe loop)
    size_t per_m = (size_t)12 * 32768;                          // 384 KB per M-tile
    size_t avail = (ws_size > off) ? (ws_size - off) : 0;
    int stripe = (int)(avail / per_m);
    if (stripe > MTILES) stripe = MTILES;
    if (stripe < 1) stripe = 1;
    short* As = (short*)(ws + off);
    int nst = (MTILES + stripe - 1) / stripe;

    hipLaunchKernelGGL(prep_weights, dim3(756), dim3(256), 0, stream,
                       Wq, Wk, Wv, Wt, Wi, W1, W5s, W1Bs);
    hipLaunchKernelGGL(proj_kernel, dim3(8, 24), dim3(256), 0, stream,
                       text, 512, W5s, 0, bt, bq, (const float*)nullptr,
                       te, qb, (float*)nullptr);
    hipLaunchKernelGGL(proj_kernel, dim3(25, 36), dim3(256), 0, stream,
                       image, 1576, W5s, 2, bi, bk, bv,
                       ieb, kb, vb);
    for (int s = 0; s < nst; ++s) {
        int m0 = s * stripe;
        int mc = (MTILES - m0 < stripe) ? (MTILES - m0) : stripe;
        hipLaunchKernelGGL(build_a, dim3(mc * 12), dim3(256), 0, stream,
                           te, ieb, As, m0);
        hipLaunchKernelGGL(gate_gemm, dim3(mc * 3), dim3(512), 0, stream,
                           As, W1Bs, b1, W2, plg, m0);
    }
    hipLaunchKernelGGL(gate_fin, dim3((NPAIRS + 255) / 256), dim3(256), 0, stream,
                       plg, b2, gateb);
    hipLaunchKernelGGL(attn_kernel, dim3(BATCH * NHEADS * 4), dim3(256), 0, stream,
                       qb, kb, vb, gateb, out);
}